// Round 1
// baseline (1689.555 us; speedup 1.0000x reference)
//
#include <hip/hip_runtime.h>

// PureCartesianTensorProductO3Sparse on MI355X (gfx950), fp32 vector-ALU.
// R3: kill the LDS-pipe bottleneck (R2 was ~7000 LDS-cycles/wave, 65% of it
// redundant weight broadcasts).
//  * Block = 1024 thr = 16 waves; wave w owns output channel o=w, lane = row
//    (TILE_R=64). Weight addresses are wave-uniform (readfirstlane) -> scalar
//    loads (sKcache) / L1 broadcast; weights NEVER touch LDS. Each weight
//    value now serves 64 rows (was 16).
//  * Inputs staged in transposed/padded layouts so every compute-side LDS
//    read is an aligned ds_read_b128 with odd quad-stride (57/53) -> no bank
//    conflicts:
//      A row: A0[16] @0 | A1pad[a][4] @16 (i in .xyz) | A2t[k][16] @80, str 228
//      B row: B0[16] @0 | B1t[j][16] @16             | B2t[k][16] @64, str 212
//  * Epilogue reuses As for output staging, flat coalesced float4 stores.

constexpr int NTHR   = 1024;
constexpr int TILE_R = 64;
constexpr int ASTR   = 228;   // floats/row, 57 quads (odd -> 8-bank spread)
constexpr int BSTR   = 212;   // floats/row, 53 quads (odd)

__device__ __forceinline__ float dot16(const float* __restrict__ w, const float* a) {
    float s0 = 0.f, s1 = 0.f, s2 = 0.f, s3 = 0.f;
#pragma unroll
    for (int k = 0; k < 4; ++k) {
        float4 v = *(const float4*)(w + 4 * k);
        s0 = fmaf(v.x, a[4 * k + 0], s0);
        s1 = fmaf(v.y, a[4 * k + 1], s1);
        s2 = fmaf(v.z, a[4 * k + 2], s2);
        s3 = fmaf(v.w, a[4 * k + 3], s3);
    }
    return (s0 + s1) + (s2 + s3);
}

// t[b] += sum_a W[o,a,b] * a0[a]   (W wave-uniform -> s_load)
__device__ __forceinline__ void accum_t(const float* __restrict__ w,
                                        const float* a0, float* t) {
#pragma unroll
    for (int a = 0; a < 16; ++a) {
        float av = a0[a];
        const float* wr = w + 16 * a;
#pragma unroll
        for (int k = 0; k < 4; ++k) {
            float4 v = *(const float4*)(wr + 4 * k);
            t[4*k+0] = fmaf(v.x, av, t[4*k+0]);
            t[4*k+1] = fmaf(v.y, av, t[4*k+1]);
            t[4*k+2] = fmaf(v.z, av, t[4*k+2]);
            t[4*k+3] = fmaf(v.w, av, t[4*k+3]);
        }
    }
}

// 16 contiguous floats from LDS -> regs (4x ds_read_b128)
__device__ __forceinline__ void ld16(const float* p, float* d) {
#pragma unroll
    for (int k = 0; k < 4; ++k) {
        float4 v = *(const float4*)(p + 4 * k);
        d[4*k+0] = v.x; d[4*k+1] = v.y; d[4*k+2] = v.z; d[4*k+3] = v.w;
    }
}

__global__ __launch_bounds__(NTHR)
void tp_kernel(const float* __restrict__ x1, const float* __restrict__ x2,
               const float* __restrict__ wgt, float* __restrict__ out, int N)
{
    __shared__ __align__(16) float As[TILE_R * ASTR];   // 58368 B
    __shared__ __align__(16) float Bs[TILE_R * BSTR];   // 54272 B -> 112640 B

    const int tid = threadIdx.x;
    const long long row0 = (long long)blockIdx.x * TILE_R;

    // ---- stage: coalesced float4 global loads, scatter into transposed/padded
    //      layouts with b32 writes (A0/B0 region goes straight through as b128).
    for (int idx = tid; idx < TILE_R * 52; idx += NTHR) {
        int rr = idx / 52, c4 = idx - rr * 52;
        float4 va = make_float4(0.f, 0.f, 0.f, 0.f), vb = va;
        if (row0 + rr < N) {
            long long g = (row0 + rr) * 416 + c4 * 4;
            va = *(const float4*)(x1 + g);
            vb = *(const float4*)(x2 + g);
        }
        if (c4 < 4) {
            *(float4*)&As[rr * ASTR + 4 * c4] = va;
            *(float4*)&Bs[rr * BSTR + 4 * c4] = vb;
        } else {
            float fa[4] = {va.x, va.y, va.z, va.w};
            float fb[4] = {vb.x, vb.y, vb.z, vb.w};
#pragma unroll
            for (int q = 0; q < 4; ++q) {
                int c = 4 * c4 + q;
                int da, db;
                if (c < 64) {                    // L=1 blocks: 16 x 3 floats
                    int n = c - 16;
                    int a = (n * 21846) >> 16;   // n/3 (exact for n<48)
                    int i = n - 3 * a;
                    da = 16 + 4 * a + i;         // A1pad[a][i]
                    db = 16 + 16 * i + a;        // B1t[i][b]
                } else {                         // L=2 blocks: 16 x 9 floats
                    int n = c - 64;
                    int a = (n * 7282) >> 16;    // n/9 (exact for n<144)
                    int k = n - 9 * a;
                    da = 80 + 16 * k + a;        // A2t[k][a]
                    db = 64 + 16 * k + a;        // B2t[k][b]
                }
                As[rr * ASTR + da] = fa[q];
                Bs[rr * BSTR + db] = fb[q];
            }
        }
    }
    __syncthreads();

    // ---- compute: wave = one o, lane = one row ----
    const int o = __builtin_amdgcn_readfirstlane((int)(threadIdx.x >> 6)); // 0..15
    const int r = tid & 63;
    const float* __restrict__ wp = wgt + o * 256;   // wave-uniform base
    const float* Ar = &As[r * ASTR];
    const float* Br = &Bs[r * BSTR];

    float a0[16], b0[16];
    ld16(Ar, a0);
    ld16(Br, b0);

    float o0 = 0.f;
    float o1[3] = {0.f, 0.f, 0.f};
    float o2[9] = {0.f,0.f,0.f,0.f,0.f,0.f,0.f,0.f,0.f};

    // path (0,0): o0 = sum_a A0[a] * sum_b W0[o,a,b] B0[b]
#pragma unroll
    for (int a = 0; a < 16; ++a)
        o0 = fmaf(a0[a], dot16(wp + 16 * a, b0), o0);

    // t1[b] = sum_a W1[o,a,b] A0[a]   (path (0,1))
    // t2[b] = sum_a W2[o,a,b] A0[a]   (path (0,2))
    float t1[16], t2[16];
#pragma unroll
    for (int k = 0; k < 16; ++k) { t1[k] = 0.f; t2[k] = 0.f; }
    accum_t(wp + 4096, a0, t1);
    accum_t(wp + 8192, a0, t2);
    // a0 dead from here.

    // fused (0,1) + (1,1): share B1t[j][:] row loads
#pragma unroll
    for (int j = 0; j < 3; ++j) {
        float br[16];
        ld16(Br + 16 + 16 * j, br);               // B1[:,j]
#pragma unroll
        for (int b = 0; b < 16; ++b)              // (0,1): o1[j] += t1[b]*B1[b,j]
            o1[j] = fmaf(t1[b], br[b], o1[j]);
#pragma unroll
        for (int a = 0; a < 16; ++a) {            // (1,1)
            float v = dot16(wp + 16384 + 16 * a, br);   // sum_b W4[o,a,b] B1[b,j]
            float4 a1 = *(const float4*)(Ar + 16 + 4 * a);
            o2[0 + j] = fmaf(a1.x, v, o2[0 + j]);
            o2[3 + j] = fmaf(a1.y, v, o2[3 + j]);
            o2[6 + j] = fmaf(a1.z, v, o2[6 + j]);
        }
    }

    // path (0,2): o2[k] += t2[b] * B2[b,k]
#pragma unroll
    for (int k = 0; k < 9; ++k) {
        float br[16];
        ld16(Br + 64 + 16 * k, br);               // B2t[k][:]
#pragma unroll
        for (int b = 0; b < 16; ++b)
            o2[k] = fmaf(t2[b], br[b], o2[k]);
    }

    // path (1,0): o1[i] += (sum_b W3[o,a,b] B0[b]) * A1[a,i]
#pragma unroll
    for (int a = 0; a < 16; ++a) {
        float u = dot16(wp + 12288 + 16 * a, b0);
        float4 a1 = *(const float4*)(Ar + 16 + 4 * a);
        o1[0] = fmaf(u, a1.x, o1[0]);
        o1[1] = fmaf(u, a1.y, o1[1]);
        o1[2] = fmaf(u, a1.z, o1[2]);
    }

    // path (2,0): o2[k] += (sum_b W5[o,a,b] B0[b]) * A2[a,k]
    {
        float u[16];
#pragma unroll
        for (int a = 0; a < 16; ++a)
            u[a] = dot16(wp + 20480 + 16 * a, b0);
#pragma unroll
        for (int k = 0; k < 9; ++k) {
            float ar[16];
            ld16(Ar + 80 + 16 * k, ar);           // A2t[k][:]
#pragma unroll
            for (int a = 0; a < 16; ++a)
                o2[k] = fmaf(u[a], ar[a], o2[k]);
        }
    }

    // ---- epilogue: stage compact 208-float output rows in As, flat stores ----
    __syncthreads();                               // all waves done reading As/Bs
    {
        float* dst = &As[r * ASTR];
        dst[o] = o0;
        dst[16 + 3 * o + 0] = o1[0];
        dst[16 + 3 * o + 1] = o1[1];
        dst[16 + 3 * o + 2] = o1[2];
#pragma unroll
        for (int k = 0; k < 9; ++k) dst[64 + 9 * o + k] = o2[k];
    }
    __syncthreads();
    for (int idx = tid; idx < TILE_R * 104; idx += NTHR) {
        int rr = idx / 104, c4 = idx - rr * 104;   // c4 in float4 units
        if (row0 + rr < N) {
            float4 v = make_float4(0.f, 0.f, 0.f, 0.f);
            if (c4 < 52) v = *(const float4*)&As[rr * ASTR + 4 * c4];
            *(float4*)&out[(row0 + rr) * 416 + 4 * c4] = v;
        }
    }
}

extern "C" void kernel_launch(void* const* d_in, const int* in_sizes, int n_in,
                              void* d_out, int out_size, void* d_ws, size_t ws_size,
                              hipStream_t stream) {
    const float* x1  = (const float*)d_in[0];
    const float* x2  = (const float*)d_in[1];
    const float* wgt = (const float*)d_in[2];
    float* out = (float*)d_out;
    const int N = in_sizes[0] / 416;
    const int grid = (N + TILE_R - 1) / TILE_R;
    hipLaunchKernelGGL(tp_kernel, dim3(grid), dim3(NTHR), 0, stream, x1, x2, wgt, out, N);
}